// Round 1
// baseline (254.843 us; speedup 1.0000x reference)
//
#include <hip/hip_runtime.h>
#include <math.h>

// Problem constants (match reference setup_inputs)
#define NN 4096
#define MM 128
#define QQ 64
#define DD 128

constexpr int BN = 128;       // n rows per block
constexpr int BQ = 64;        // q cols per block (one m per block)
constexpr int TN = 8;         // per-thread n rows
constexpr int TQ = 4;         // per-thread q cols
constexpr int LDA = DD + 4;   // padded LDS stride (keeps 16B alignment: 132*4=528B)

// dens_per_cluster[n,m] = sum_q exp(-(a2[n] - 2*ab + b2[m,q]) * 0.5/var)
__global__ __launch_bounds__(256, 1)
void kde_dens_kernel(const float* __restrict__ A,   // [NN][DD]
                     const float* __restrict__ B,   // [MM][QQ][DD]
                     const float* __restrict__ var, // [1]
                     float* __restrict__ dpc)       // [NN][MM]
{
    __shared__ float As[BN][LDA];
    __shared__ float Bs[BQ][LDA];
    __shared__ float a2s[BN];
    __shared__ float b2s[BQ];
    __shared__ float red[BN][17];   // 16 partials per row, +1 pad

    const int m  = blockIdx.y;          // 0..127
    const int n0 = blockIdx.x * BN;     // n block start
    const int t  = threadIdx.x;         // 0..255

    // ---- stage A tile: 128 rows x 128 floats = 4096 float4, 16 per thread ----
    const float4* Ag = (const float4*)(A + (size_t)n0 * DD);
    #pragma unroll
    for (int i = 0; i < (BN * DD / 4) / 256; ++i) {
        int idx = t + i * 256;              // 0..4095
        int r = idx >> 5;                   // 32 float4 per row
        int c = idx & 31;
        *(float4*)&As[r][c * 4] = Ag[idx];
    }
    // ---- stage B tile: 64 rows x 128 floats = 2048 float4, 8 per thread ----
    const float4* Bg = (const float4*)(B + (size_t)m * QQ * DD);
    #pragma unroll
    for (int i = 0; i < (BQ * DD / 4) / 256; ++i) {
        int idx = t + i * 256;              // 0..2047
        int r = idx >> 5;
        int c = idx & 31;
        *(float4*)&Bs[r][c * 4] = Bg[idx];
    }
    __syncthreads();

    // ---- squared norms from LDS (once per block, negligible vs main loop) ----
    if (t < BN) {
        float s = 0.f;
        for (int k = 0; k < DD; ++k) { float v = As[t][k]; s += v * v; }
        a2s[t] = s;
    } else if (t < BN + BQ) {
        int r = t - BN;
        float s = 0.f;
        for (int k = 0; k < DD; ++k) { float v = Bs[r][k]; s += v * v; }
        b2s[r] = s;
    }
    __syncthreads();

    // ---- main GEMM micro-kernel: 8x4 per thread, k unrolled by 4 (float4) ----
    const int tx = t & 15;          // 0..15 -> q groups
    const int ty = t >> 4;          // 0..15 -> n groups
    const int rn = ty * TN;         // 0..120
    const int rq = tx * TQ;         // 0..60

    float acc[TN][TQ] = {};
    for (int k = 0; k < DD; k += 4) {
        float4 a[TN];
        float4 b[TQ];
        #pragma unroll
        for (int i = 0; i < TN; ++i) a[i] = *(const float4*)&As[rn + i][k];
        #pragma unroll
        for (int j = 0; j < TQ; ++j) b[j] = *(const float4*)&Bs[rq + j][k];
        #pragma unroll
        for (int i = 0; i < TN; ++i)
            #pragma unroll
            for (int j = 0; j < TQ; ++j)
                acc[i][j] += a[i].x * b[j].x + a[i].y * b[j].y
                           + a[i].z * b[j].z + a[i].w * b[j].w;
    }

    // ---- epilogue: exp + partial sum over this thread's 4 q cols ----
    const float hinv = 0.5f / var[0];    // dens = exp(-(a2 - 2ab + b2) * hinv)
    float part[TN];
    #pragma unroll
    for (int i = 0; i < TN; ++i) {
        const float a2 = a2s[rn + i];
        float p = 0.f;
        #pragma unroll
        for (int j = 0; j < TQ; ++j) {
            float e = (2.f * acc[i][j] - a2 - b2s[rq + j]) * hinv;
            p += __expf(e);
        }
        part[i] = p;
    }

    // ---- reduce across the 16 tx groups per row ----
    #pragma unroll
    for (int i = 0; i < TN; ++i) red[rn + i][tx] = part[i];
    __syncthreads();
    if (t < BN) {
        float s = 0.f;
        #pragma unroll
        for (int x = 0; x < 16; ++x) s += red[t][x];
        dpc[(size_t)(n0 + t) * MM + m] = s;
    }
}

// prob[n,m] = dpc[n,m] / (sum_m dpc[n,:] + 1e-10)
__global__ __launch_bounds__(128)
void kde_norm_kernel(const float* __restrict__ dpc, float* __restrict__ out)
{
    const int n = blockIdx.x;
    const int t = threadIdx.x;          // 0..127
    const float v = dpc[(size_t)n * MM + t];

    float s = v;
    #pragma unroll
    for (int off = 32; off > 0; off >>= 1) s += __shfl_down(s, off); // wave64 reduce
    __shared__ float ws[2];
    if ((t & 63) == 0) ws[t >> 6] = s;
    __syncthreads();
    const float tot = ws[0] + ws[1];
    out[(size_t)n * MM + t] = v / (tot + 1e-10f);
}

extern "C" void kernel_launch(void* const* d_in, const int* in_sizes, int n_in,
                              void* d_out, int out_size, void* d_ws, size_t ws_size,
                              hipStream_t stream) {
    const float* A   = (const float*)d_in[0];   // [4096][128]
    const float* B   = (const float*)d_in[1];   // [128][64][128]
    const float* var = (const float*)d_in[2];   // [1]
    float* out = (float*)d_out;                 // [4096][128]
    float* dpc = (float*)d_ws;                  // [4096][128] scratch (2 MB)

    dim3 g1(NN / BN, MM);                       // (32, 128) = 4096 blocks
    kde_dens_kernel<<<g1, 256, 0, stream>>>(A, B, var, dpc);
    kde_norm_kernel<<<NN, 128, 0, stream>>>(dpc, out);
}

// Round 2
// 94.251 us; speedup vs baseline: 2.7039x; 2.7039x over previous
//
#include <hip/hip_runtime.h>
#include <hip/hip_bf16.h>
#include <math.h>

// Problem constants (match reference setup_inputs)
#define NN 4096
#define MM 128
#define QQ 64
#define DD 128
#define CC (MM * QQ)          // 8192 gemm "columns" (flattened m,q)

typedef short bf16x8 __attribute__((ext_vector_type(8)));  // 8 bf16 = 4 VGPRs
typedef float f32x4  __attribute__((ext_vector_type(4)));

#define LDB 136               // padded LDS row stride in bf16 (272 B ≡ 4 dwords mod 32 banks)

static __device__ inline unsigned short f2bf(float f) {
    __hip_bfloat16 h = __float2bfloat16(f);
    return *reinterpret_cast<unsigned short*>(&h);
}

// ---- pre-kernel: exact fp32 squared norms: ws[0..4096)=a2, ws[4096..12288)=b2 ----
__global__ __launch_bounds__(64)
void sqnorm_kernel(const float* __restrict__ A, const float* __restrict__ B,
                   float* __restrict__ ws)
{
    const int row = blockIdx.x;            // 0..12287
    const int t   = threadIdx.x;           // 0..63
    const float* src = (row < NN) ? (A + (size_t)row * DD)
                                  : (B + (size_t)(row - NN) * DD);
    float v0 = src[t], v1 = src[t + 64];
    float s = v0 * v0 + v1 * v1;
    #pragma unroll
    for (int off = 32; off > 0; off >>= 1) s += __shfl_down(s, off);
    if (t == 0) ws[row] = s;
}

// ---- main: bf16 MFMA GEMM (one-shot K=128) + fused exp + Q-reduction ----
// Block (bx, by): rows n0=bx*128, gemm-cols c0=by*128 (= m pair {2by, 2by+1}).
// 4 waves: wave w covers rows rowhalf*64, cols colhalf*64 (rowhalf=w>>1, colhalf=w&1).
__global__ __launch_bounds__(256, 2)
void kde_mfma_kernel(const float* __restrict__ A,   // [NN][DD] fp32
                     const float* __restrict__ B,   // [CC][DD] fp32 (M*Q rows)
                     const float* __restrict__ var, // [1]
                     const float* __restrict__ ws,  // a2[NN] then b2[CC]
                     float* __restrict__ dpc)       // [NN][MM] (= d_out, pre-normalize)
{
    __shared__ unsigned short As[128][LDB];
    __shared__ unsigned short Bs[128][LDB];
    __shared__ float a2s[128];
    __shared__ float b2s[128];

    const int t  = threadIdx.x;            // 0..255
    const int n0 = blockIdx.x * 128;
    const int c0 = blockIdx.y * 128;

    // stage + convert A tile (128x128 fp32 -> bf16): 4096 float4, 16/thread
    const float4* Ag = (const float4*)(A + (size_t)n0 * DD);
    const float4* Bg = (const float4*)(B + (size_t)c0 * DD);
    #pragma unroll
    for (int i = 0; i < 16; ++i) {
        int idx = t + i * 256;             // 0..4095
        int r = idx >> 5;                  // 32 float4 per row
        int c4 = idx & 31;
        float4 v = Ag[idx];
        ushort4 u;
        u.x = f2bf(v.x); u.y = f2bf(v.y); u.z = f2bf(v.z); u.w = f2bf(v.w);
        *(ushort4*)&As[r][c4 * 4] = u;
        float4 w = Bg[idx];
        ushort4 uw;
        uw.x = f2bf(w.x); uw.y = f2bf(w.y); uw.z = f2bf(w.z); uw.w = f2bf(w.w);
        *(ushort4*)&Bs[r][c4 * 4] = uw;
    }
    // stage norms
    if (t < 128)            a2s[t]       = ws[n0 + t];
    else                    b2s[t - 128] = ws[NN + c0 + (t - 128)];
    __syncthreads();

    // wave / lane decomposition
    const int w    = t >> 6;
    const int lane = t & 63;
    const int l15  = lane & 15;
    const int q    = lane >> 4;            // quad 0..3
    const int rbase = (w >> 1) * 64;       // LDS-local row base for this wave
    const int cbase = (w & 1) * 64;        // LDS-local col base

    f32x4 acc[4][4] = {};
    #pragma unroll
    for (int ks = 0; ks < 4; ++ks) {       // K = 4 * 32
        bf16x8 af[4], bf[4];
        #pragma unroll
        for (int i = 0; i < 4; ++i)
            af[i] = *(const bf16x8*)&As[rbase + i * 16 + l15][ks * 32 + q * 8];
        #pragma unroll
        for (int j = 0; j < 4; ++j)
            bf[j] = *(const bf16x8*)&Bs[cbase + j * 16 + l15][ks * 32 + q * 8];
        #pragma unroll
        for (int i = 0; i < 4; ++i)
            #pragma unroll
            for (int j = 0; j < 4; ++j)
                acc[i][j] = __builtin_amdgcn_mfma_f32_16x16x32_bf16(
                                af[i], bf[j], acc[i][j], 0, 0, 0);
    }

    // epilogue: dens = exp((2ab - a2 - b2) * 0.5/var); sum over this wave's 64 cols (one m)
    const float hinv = 0.5f / var[0];
    float rowsum[4][4] = {};               // [row-tile i][reg]
    #pragma unroll
    for (int i = 0; i < 4; ++i) {
        #pragma unroll
        for (int reg = 0; reg < 4; ++reg) {
            const float a2 = a2s[rbase + i * 16 + q * 4 + reg];
            float p = 0.f;
            #pragma unroll
            for (int j = 0; j < 4; ++j) {
                const float b2 = b2s[cbase + j * 16 + l15];
                const float v  = acc[i][j][reg];
                p += __expf((2.f * v - a2 - b2) * hinv);
            }
            rowsum[i][reg] = p;
        }
    }
    // butterfly-sum across the 16 lanes of each quad (cols)
    #pragma unroll
    for (int mask = 1; mask < 16; mask <<= 1)
        #pragma unroll
        for (int i = 0; i < 4; ++i)
            #pragma unroll
            for (int reg = 0; reg < 4; ++reg)
                rowsum[i][reg] += __shfl_xor(rowsum[i][reg], mask, 64);

    // write: wave's col half is one m; 16 lanes (l15<4) each write 4 rows
    const int m = (blockIdx.y << 1) + (w & 1);
    if (l15 < 4) {
        const int i = l15;
        #pragma unroll
        for (int reg = 0; reg < 4; ++reg) {
            const int gn = n0 + rbase + i * 16 + q * 4 + reg;
            dpc[(size_t)gn * MM + m] = rowsum[i][reg];
        }
    }
}

// ---- in-place row-normalize over M: out[n,m] /= (sum_m + 1e-10) ----
__global__ __launch_bounds__(128)
void kde_norm_kernel(float* __restrict__ out)
{
    const int n = blockIdx.x;
    const int t = threadIdx.x;             // 0..127
    const float v = out[(size_t)n * MM + t];
    float s = v;
    #pragma unroll
    for (int off = 32; off > 0; off >>= 1) s += __shfl_down(s, off);
    __shared__ float wsum[2];
    if ((t & 63) == 0) wsum[t >> 6] = s;
    __syncthreads();
    const float tot = wsum[0] + wsum[1];
    out[(size_t)n * MM + t] = v / (tot + 1e-10f);
}

extern "C" void kernel_launch(void* const* d_in, const int* in_sizes, int n_in,
                              void* d_out, int out_size, void* d_ws, size_t ws_size,
                              hipStream_t stream) {
    const float* A   = (const float*)d_in[0];   // [4096][128]
    const float* B   = (const float*)d_in[1];   // [128][64][128] = [8192][128]
    const float* var = (const float*)d_in[2];   // [1]
    float* out = (float*)d_out;                 // [4096][128]
    float* nw  = (float*)d_ws;                  // a2[4096] + b2[8192] = 48 KB

    sqnorm_kernel<<<NN + CC, 64, 0, stream>>>(A, B, nw);
    dim3 g(NN / 128, CC / 128);                 // (32, 64) = 2048 blocks
    kde_mfma_kernel<<<g, 256, 0, stream>>>(A, B, var, nw, out);
    kde_norm_kernel<<<NN, 128, 0, stream>>>(out);
}

// Round 3
// 89.439 us; speedup vs baseline: 2.8493x; 1.0538x over previous
//
#include <hip/hip_runtime.h>
#include <hip/hip_bf16.h>
#include <math.h>

// Problem constants (match reference setup_inputs)
#define NN 4096
#define MM 128
#define QQ 64
#define DD 128
#define CC (MM * QQ)          // 8192 gemm "columns" (flattened m,q)

typedef short bf16x8 __attribute__((ext_vector_type(8)));  // 8 bf16 = 4 VGPRs
typedef float f32x4  __attribute__((ext_vector_type(4)));

static __device__ inline unsigned short f2bf(float f) {
    __hip_bfloat16 h = __float2bfloat16(f);
    return *reinterpret_cast<unsigned short*>(&h);
}

// ---- pre-kernel: fp32->bf16 convert + exact fp32 squared norms ----
// One 64-lane wave per row (12288 rows total), 4 rows per block.
__global__ __launch_bounds__(256)
void prep_kernel(const float* __restrict__ A, const float* __restrict__ B,
                 unsigned short* __restrict__ Abf, unsigned short* __restrict__ Bbf,
                 float* __restrict__ a2, float* __restrict__ b2)
{
    const int row  = blockIdx.x * 4 + (threadIdx.x >> 6);   // 0..12287
    const int lane = threadIdx.x & 63;
    const float* src;
    unsigned short* dst;
    float* nrm;
    if (row < NN) { src = A + (size_t)row * DD; dst = Abf + (size_t)row * DD; nrm = a2 + row; }
    else {
        int r = row - NN;
        src = B + (size_t)r * DD; dst = Bbf + (size_t)r * DD; nrm = b2 + r;
    }
    float2 v = ((const float2*)src)[lane];
    ushort2 u; u.x = f2bf(v.x); u.y = f2bf(v.y);
    ((ushort2*)dst)[lane] = u;
    float s = v.x * v.x + v.y * v.y;
    #pragma unroll
    for (int off = 32; off > 0; off >>= 1) s += __shfl_down(s, off);
    if (lane == 0) *nrm = s;
}

// ---- main: bf16 MFMA GEMM (one-shot K=128) + fused exp + Q-reduction ----
// LDS tile: 256 rows x 128 bf16 (A rows 0..127 = n-tile, rows 128..255 = c-tile).
// Pad-free (global_load_lds requirement); bank conflicts broken by XOR chunk
// swizzle: LDS(row, cb) holds global chunk (row, cb ^ (row&7)), cb = 16B chunk.
__global__ __launch_bounds__(256, 2)
void kde_mfma_kernel(const unsigned short* __restrict__ Abf,  // [NN][DD] bf16
                     const unsigned short* __restrict__ Bbf,  // [CC][DD] bf16
                     const float* __restrict__ var,
                     const float* __restrict__ a2w,           // [NN]
                     const float* __restrict__ b2w,           // [CC]
                     float* __restrict__ dpc)                 // [NN][MM]
{
    __shared__ unsigned short Tile[256 * DD];   // 64 KB
    __shared__ float a2s[128];
    __shared__ float b2s[128];

    // XCD-aware swizzle: XCD x (= blockIdx.x % 8) owns by in [8x, 8x+8).
    const int lin = blockIdx.x;
    const int xcd = lin & 7;
    const int loc = lin >> 3;                  // 0..255
    const int by  = (xcd << 3) | (loc >> 5);   // 0..63
    const int bx  = loc & 31;                  // 0..31
    const int n0  = bx * 128;
    const int c0  = by * 128;

    const int t    = threadIdx.x;
    const int w    = t >> 6;
    const int lane = t & 63;

    // ---- async staging: 4096 16B chunks, 16 instrs/wave, swizzled source ----
    const unsigned short* Ab = Abf + (size_t)n0 * DD;
    const unsigned short* Bb = Bbf + (size_t)c0 * DD;
    #pragma unroll
    for (int i = 0; i < 16; ++i) {
        const int slot = w * 1024 + i * 64 + lane;   // 0..4095
        const int r    = slot >> 4;                  // LDS row 0..255
        const int cb   = slot & 15;                  // chunk-in-row
        const int scb  = cb ^ (r & 7);               // swizzled source chunk
        const unsigned short* g = (r < 128) ? (Ab + r * DD + scb * 8)
                                            : (Bb + (r - 128) * DD + scb * 8);
        unsigned short* lbase = &Tile[(w * 1024 + i * 64) * 8];  // wave-uniform
        __builtin_amdgcn_global_load_lds(
            (const __attribute__((address_space(1))) unsigned int*)g,
            (__attribute__((address_space(3))) unsigned int*)lbase,
            16, 0, 0);
    }
    if (t < 128)            a2s[t]       = a2w[n0 + t];
    else                    b2s[t - 128] = b2w[c0 + (t - 128)];
    __syncthreads();   // drains vmcnt(0) incl. global_load_lds

    // ---- MFMA micro-kernel: wave w -> rows (w>>1)*64, cols (w&1)*64 ----
    const int l15   = lane & 15;
    const int q     = lane >> 4;
    const int rbase = (w >> 1) * 64;
    const int cbase = (w & 1) * 64;
    const int xr    = l15 & 7;                 // row&7 for all frag rows

    f32x4 acc[4][4] = {};
    #pragma unroll
    for (int ks = 0; ks < 4; ++ks) {           // K = 4 * 32
        const int off = ((ks * 4 + q) ^ xr) * 8;   // swizzled ushort offset
        bf16x8 af[4], bf[4];
        #pragma unroll
        for (int i = 0; i < 4; ++i)
            af[i] = *(const bf16x8*)&Tile[(rbase + i * 16 + l15) * DD + off];
        #pragma unroll
        for (int j = 0; j < 4; ++j)
            bf[j] = *(const bf16x8*)&Tile[(128 + cbase + j * 16 + l15) * DD + off];
        #pragma unroll
        for (int i = 0; i < 4; ++i)
            #pragma unroll
            for (int j = 0; j < 4; ++j)
                acc[i][j] = __builtin_amdgcn_mfma_f32_16x16x32_bf16(
                                af[i], bf[j], acc[i][j], 0, 0, 0);
    }

    // ---- epilogue: dens = exp((2ab - a2 - b2) * 0.5/var); sum over 64 cols (one m) ----
    const float hinv = 0.5f / var[0];
    float rowsum[4][4];
    #pragma unroll
    for (int i = 0; i < 4; ++i) {
        #pragma unroll
        for (int reg = 0; reg < 4; ++reg) {
            const float a2 = a2s[rbase + i * 16 + q * 4 + reg];
            float p = 0.f;
            #pragma unroll
            for (int j = 0; j < 4; ++j) {
                const float b2 = b2s[cbase + j * 16 + l15];
                p += __expf((2.f * acc[i][j][reg] - a2 - b2) * hinv);
            }
            rowsum[i][reg] = p;
        }
    }
    #pragma unroll
    for (int mask = 1; mask < 16; mask <<= 1)
        #pragma unroll
        for (int i = 0; i < 4; ++i)
            #pragma unroll
            for (int reg = 0; reg < 4; ++reg)
                rowsum[i][reg] += __shfl_xor(rowsum[i][reg], mask, 64);

    const int m = (by << 1) + (w & 1);
    if (l15 < 4) {
        const int i = l15;
        #pragma unroll
        for (int reg = 0; reg < 4; ++reg) {
            const int gn = n0 + rbase + i * 16 + q * 4 + reg;
            dpc[(size_t)gn * MM + m] = rowsum[i][reg];
        }
    }
}

// ---- in-place row-normalize over M: out[n,m] /= (sum_m + 1e-10) ----
__global__ __launch_bounds__(128)
void kde_norm_kernel(float* __restrict__ out)
{
    const int n = blockIdx.x;
    const int t = threadIdx.x;
    const float v = out[(size_t)n * MM + t];
    float s = v;
    #pragma unroll
    for (int off = 32; off > 0; off >>= 1) s += __shfl_down(s, off);
    __shared__ float wsum[2];
    if ((t & 63) == 0) wsum[t >> 6] = s;
    __syncthreads();
    const float tot = wsum[0] + wsum[1];
    out[(size_t)n * MM + t] = v / (tot + 1e-10f);
}

extern "C" void kernel_launch(void* const* d_in, const int* in_sizes, int n_in,
                              void* d_out, int out_size, void* d_ws, size_t ws_size,
                              hipStream_t stream) {
    const float* A   = (const float*)d_in[0];   // [4096][128]
    const float* B   = (const float*)d_in[1];   // [128][64][128] = [8192][128]
    const float* var = (const float*)d_in[2];   // [1]
    float* out = (float*)d_out;                 // [4096][128]

    unsigned short* Abf = (unsigned short*)d_ws;        // 1 MB
    unsigned short* Bbf = Abf + (size_t)NN * DD;        // 2 MB
    float* a2 = (float*)(Bbf + (size_t)CC * DD);        // 16 KB
    float* b2 = a2 + NN;                                // 32 KB

    prep_kernel<<<(NN + CC) / 4, 256, 0, stream>>>(A, B, Abf, Bbf, a2, b2);
    kde_mfma_kernel<<<2048, 256, 0, stream>>>(Abf, Bbf, var, a2, b2, out);
    kde_norm_kernel<<<NN, 128, 0, stream>>>(out);
}